// Round 10
// baseline (493.928 us; speedup 1.0000x reference)
//
#include <hip/hip_runtime.h>

#define BB 64
#define NN 8192
#define MM 128
#define HH 512
#define KLSTM 896   // 384 (x|pr0|pr1) + 512 (h0)
#define JTOT 2048
#define COLS 658    // 134 (ro0) + 390 (wo0) + 134 (ro1)
#define OUTN 128
#define CHUNKS 32   // 8192/32 = 256 rows per chunk
#define PROW 388    // PART row stride
#define RSTR 672    // RPART col stride (21 tiles * 32)

__device__ __forceinline__ float sigf(float x){ return 1.0f/(1.0f+__expf(-x)); }
__device__ __forceinline__ float tanhf_f(float x){ return 1.0f - 2.0f/(__expf(2.0f*x)+1.0f); }
__device__ __forceinline__ float softplusf_(float x){ return (x>20.0f)? x : log1pf(expf(x)); }

// ---------- 1. LSTM gemm, 4-way k-split: GPART[ks][b][j] ----------
__global__ __launch_bounds__(128) void k_lstm_split(
    const float* __restrict__ x, const float* __restrict__ pr,
    const float* __restrict__ h0, const float* __restrict__ Wih,
    const float* __restrict__ Whh, float* __restrict__ GPART)
{
  __shared__ float a_s[64][68];   // [kk][b]
  __shared__ float w_s[64][36];   // [kk][j]
  int tid = threadIdx.x;
  int jt = blockIdx.x, ks = blockIdx.y;
  int jbase = jt*32;
  int cbeg = (ks<2)? ks*4 : 8 + (ks-2)*3;   // chunks 4,4,3,3 of 64k
  int cend = (ks<2)? cbeg+4 : cbeg+3;
  int jq = tid & 7, bq = tid >> 3;          // jq 0..7 (4j), bq 0..15 (4b)
  float4 acc0={0,0,0,0}, acc1={0,0,0,0}, acc2={0,0,0,0}, acc3={0,0,0,0};
  for (int c=cbeg; c<cend; ++c){
    int kc = c*64;
    __syncthreads();
    #pragma unroll
    for (int i=0;i<32;i++){
      int idx = tid + i*128;
      int kk = idx & 63, p = idx >> 6;
      int kg = kc + kk;
      float iv;
      if (kg < 128)      iv = x[p*128 + kg];
      else if (kg < 256) iv = pr[p*MM + (kg-128)];
      else if (kg < 384) iv = pr[BB*MM + p*MM + (kg-256)];
      else               iv = h0[p*HH + (kg-384)];
      a_s[kk][p] = iv;
    }
    #pragma unroll
    for (int i=0;i<16;i++){
      int idx = tid + i*128;
      int kk = idx & 63, j = idx >> 6;
      int kg = kc + kk;
      int jj = jbase + j;
      float wv = (kg < 384) ? Wih[(size_t)jj*384 + kg]
                            : Whh[(size_t)jj*512 + (kg-384)];
      w_s[kk][j] = wv;
    }
    __syncthreads();
    #pragma unroll 4
    for (int kk=0; kk<64; ++kk){
      float4 av = *(const float4*)&a_s[kk][bq*4];
      float4 wv = *(const float4*)&w_s[kk][jq*4];
      acc0.x += av.x*wv.x; acc0.y += av.x*wv.y; acc0.z += av.x*wv.z; acc0.w += av.x*wv.w;
      acc1.x += av.y*wv.x; acc1.y += av.y*wv.y; acc1.z += av.y*wv.z; acc1.w += av.y*wv.w;
      acc2.x += av.z*wv.x; acc2.y += av.z*wv.y; acc2.z += av.z*wv.z; acc2.w += av.z*wv.w;
      acc3.x += av.w*wv.x; acc3.y += av.w*wv.y; acc3.z += av.w*wv.z; acc3.w += av.w*wv.w;
    }
  }
  size_t base = (size_t)ks*BB*JTOT;
  int col = jbase + jq*4;
  *(float4*)&GPART[base + (size_t)(bq*4+0)*JTOT + col] = acc0;
  *(float4*)&GPART[base + (size_t)(bq*4+1)*JTOT + col] = acc1;
  *(float4*)&GPART[base + (size_t)(bq*4+2)*JTOT + col] = acc2;
  *(float4*)&GPART[base + (size_t)(bq*4+3)*JTOT + col] = acc3;
}

// ---------- 2. head gemm, 4-way k-split, LSTM activation fused into staging ----------
// RPART[ks][b][col]; ctrl recomputed on the fly from GPART (bit-identical per entry)
__global__ __launch_bounds__(128) void k_head_split(
    const float* __restrict__ GPART, const float* __restrict__ bih,
    const float* __restrict__ bhh, const float* __restrict__ c0,
    const float* __restrict__ Wr, const float* __restrict__ Ww,
    float* __restrict__ RPART)
{
  __shared__ float c_s[64][68];
  __shared__ float w_s[64][36];
  int tid = threadIdx.x;
  int ct = blockIdx.x, ks = blockIdx.y;
  int cbase = ct*32;
  int jq = tid & 7, bq = tid >> 3;
  float4 acc0={0,0,0,0}, acc1={0,0,0,0}, acc2={0,0,0,0}, acc3={0,0,0,0};
  for (int cc=0; cc<2; ++cc){
    int kc = ks*128 + cc*64;
    __syncthreads();
    #pragma unroll
    for (int i=0;i<32;i++){
      int idx = tid + i*128;
      int kk = idx & 63, p = idx >> 6;
      int h = kc + kk;
      float g0 = bih[h]      + bhh[h];
      float g1 = bih[HH+h]   + bhh[HH+h];
      float g2 = bih[2*HH+h] + bhh[2*HH+h];
      float g3 = bih[3*HH+h] + bhh[3*HH+h];
      #pragma unroll
      for (int ks2=0; ks2<4; ++ks2){
        const float* gp = GPART + ((size_t)ks2*BB + p)*JTOT;
        g0 += gp[h]; g1 += gp[HH+h]; g2 += gp[2*HH+h]; g3 += gp[3*HH+h];
      }
      float i_ = sigf(g0), f_ = sigf(g1), gg = tanhf_f(g2), o_ = sigf(g3);
      c_s[kk][p] = o_*tanhf_f(f_*c0[p*HH + h] + i_*gg);
    }
    #pragma unroll
    for (int i=0;i<16;i++){
      int idx = tid + i*128;
      int kk = idx & 63, j = idx >> 6;
      int col = cbase + j;
      int h = kc + kk;
      float wv = 0.0f;
      if (col < 134)       wv = Wr[(size_t)col*HH + h];
      else if (col < 524)  wv = Ww[(size_t)(col-134)*HH + h];
      else if (col < COLS) wv = Wr[(size_t)(134 + col-524)*HH + h];
      w_s[kk][j] = wv;
    }
    __syncthreads();
    #pragma unroll 4
    for (int kk=0; kk<64; ++kk){
      float4 av = *(const float4*)&c_s[kk][bq*4];
      float4 wv = *(const float4*)&w_s[kk][jq*4];
      acc0.x += av.x*wv.x; acc0.y += av.x*wv.y; acc0.z += av.x*wv.z; acc0.w += av.x*wv.w;
      acc1.x += av.y*wv.x; acc1.y += av.y*wv.y; acc1.z += av.y*wv.z; acc1.w += av.y*wv.w;
      acc2.x += av.z*wv.x; acc2.y += av.z*wv.y; acc2.z += av.z*wv.z; acc2.w += av.z*wv.w;
      acc3.x += av.w*wv.x; acc3.y += av.w*wv.y; acc3.z += av.w*wv.z; acc3.w += av.w*wv.w;
    }
  }
  size_t base = (size_t)ks*BB*RSTR;
  int col = cbase + jq*4;
  *(float4*)&RPART[base + (size_t)(bq*4+0)*RSTR + col] = acc0;
  *(float4*)&RPART[base + (size_t)(bq*4+1)*RSTR + col] = acc1;
  *(float4*)&RPART[base + (size_t)(bq*4+2)*RSTR + col] = acc2;
  *(float4*)&RPART[base + (size_t)(bq*4+3)*RSTR + col] = acc3;
}

// ---------- 3. params: reduce RPART(+bias) -> COEF8[b][m][8], SCAL ----------
__global__ __launch_bounds__(256) void k_params(
    const float* __restrict__ RPART, const float* __restrict__ br,
    const float* __restrict__ bw, float* __restrict__ COEF8,
    float* __restrict__ scal)
{
  int b = blockIdx.x, tid = threadIdx.x;
  __shared__ float ro[RSTR];
  __shared__ float wred[2][5];
  for (int idx=tid; idx<COLS; idx+=256){
    float s = (idx<134)? br[idx] : (idx<524)? bw[idx-134] : br[134 + idx-524];
    #pragma unroll
    for (int ks=0; ks<4; ++ks) s += RPART[((size_t)ks*BB + b)*RSTR + idx];
    ro[idx] = s;
  }
  __syncthreads();
  int m = tid & 127;
  float k0 = ro[m], kw = ro[134+m], k1 = ro[524+m];
  float e  = sigf(ro[268+m]);
  float a  = ro[396+m];
  if (tid < 128){
    float* c8 = COEF8 + ((size_t)b*MM + m)*8;
    *(float4*)c8     = make_float4(k0, kw, k1, e*k1);
    *(float4*)(c8+4) = make_float4(e, e*e, a, a*e);
  }
  float r0=k0*k0, r1=kw*kw, r2=k1*k1, r3=a*k1, r4=a*a;
  #pragma unroll
  for (int off=32; off; off>>=1){
    r0 += __shfl_xor(r0, off);
    r1 += __shfl_xor(r1, off);
    r2 += __shfl_xor(r2, off);
    r3 += __shfl_xor(r3, off);
    r4 += __shfl_xor(r4, off);
  }
  if (tid < 128 && (tid & 63) == 0){
    int w = tid >> 6;
    wred[w][0]=r0; wred[w][1]=r1; wred[w][2]=r2; wred[w][3]=r3; wred[w][4]=r4;
  }
  __syncthreads();
  if (tid < 3){
    float knsq = wred[0][tid] + wred[1][tid];
    float kn = fmaxf(sqrtf(knsq), 1e-8f);
    int base = (tid==0)? 0 : (tid==1)? 134 : 524;
    float beta  = softplusf_(ro[base+128]);
    float g     = sigf(ro[base+129]);
    float s0r = ro[base+130], s1r = ro[base+131], s2r = ro[base+132];
    float mx = fmaxf(s0r, fmaxf(s1r, s2r));
    float es0 = __expf(s0r-mx), es1 = __expf(s1r-mx), es2 = __expf(s2r-mx);
    float es = es0+es1+es2;
    float gamma = 1.0f + softplusf_(ro[base+133]);
    float* sc = scal + ((size_t)tid*BB + b)*8;
    sc[0]=beta; sc[1]=g; sc[2]=es0/es; sc[3]=es1/es; sc[4]=es2/es; sc[5]=gamma; sc[6]=kn;
  }
  if (tid == 3) scal[((size_t)3*BB + b)*8 + 0] = wred[0][3] + wred[1][3];  // a.kr1
  if (tid == 4) scal[((size_t)3*BB + b)*8 + 1] = wred[0][4] + wred[1][4];  // a.a
}

// ---------- 4. pass A: XCD-affine; LDS transpose; 9 per-row scalars ----------
__global__ __launch_bounds__(256) void k_passA(
    const float* __restrict__ mem, const float* __restrict__ COEF8,
    float* __restrict__ OUT9)
{
  const size_t S = (size_t)BB*NN;
  int l = blockIdx.x;
  int xcd = l & 7, i = l >> 3;            // i in [0,256)
  int b = xcd*8 + (i >> 5);
  int chunk = i & 31;
  int tid = threadIdx.x;
  __shared__ float vtile[32][257];
  const float4* cb = (const float4*)(COEF8 + (size_t)b*MM*8);  // wave-uniform -> s_load
  int rowbase = chunk*256;
  float acc[9];
  #pragma unroll
  for (int q=0;q<9;q++) acc[q] = 0.f;
  for (int kc=0; kc<4; ++kc){
    __syncthreads();
    #pragma unroll
    for (int ii=0;ii<8;ii++){
      int f = tid + ii*256;
      int r = f >> 3, k4 = f & 7;
      float4 v = *(const float4*)(mem + ((size_t)b*NN + rowbase + r)*MM + kc*32 + k4*4);
      vtile[k4*4+0][r] = v.x;
      vtile[k4*4+1][r] = v.y;
      vtile[k4*4+2][r] = v.z;
      vtile[k4*4+3][r] = v.w;
    }
    __syncthreads();
    #pragma unroll
    for (int kk=0; kk<32; ++kk){
      int kg = kc*32 + kk;
      float4 cA = cb[kg*2];
      float4 cB = cb[kg*2+1];
      float v  = vtile[kk][tid];
      float vv = v*v;
      acc[0] += v*cA.x;  acc[1] += v*cA.y;  acc[2] += vv;
      acc[3] += v*cA.z;  acc[4] += v*cA.w;
      acc[5] += vv*cB.x; acc[6] += vv*cB.y;
      acc[7] += v*cB.z;  acc[8] += v*cB.w;
    }
  }
  size_t p = (size_t)b*NN + rowbase + tid;
  #pragma unroll
  for (int q=0;q<9;q++) OUT9[(size_t)q*S + p] = acc[q];
}

// ---------- 5. fused addressing (512 thr, XCD-affine), wave-shuffle reductions ----------
__global__ __launch_bounds__(512) void k_addr(
    const float* __restrict__ OUT9, const float* __restrict__ scal,
    const float* __restrict__ pwr, const float* __restrict__ pww,
    float* __restrict__ WR0 /* +S = WW0 */, float* __restrict__ WR1)
{
  const size_t S = (size_t)BB*NN;
  int l = blockIdx.x;
  int xcd = l & 7, j = l >> 3;            // j in [0,16)
  int role = j >> 3;
  int b = xcd*8 + (j & 7);
  int tid = threadIdx.x;
  int lane = tid & 63, wid = tid >> 6;    // 8 waves
  __shared__ float buf[NN];
  __shared__ float wred[6][8];
  float wfin[16];

  // ----- chain 1: head-0, which = role -----
  {
    const float* numb = OUT9 + (size_t)role*S + (size_t)b*NN;
    const float* ssb  = OUT9 + 2*S + (size_t)b*NN;
    const float* wprev = ((role==0)? pwr : pww) + (size_t)b*NN;
    float* wo = WR0 + (size_t)role*S + (size_t)b*NN;
    const float* sc = scal + ((size_t)role*BB + b)*8;
    float beta=sc[0], g=sc[1], s0=sc[2], s1=sc[3], s2=sc[4], gamma=sc[5], kn=sc[6];
    float lreg[16];
    float lmax = -1e30f;
    #pragma unroll
    for (int i=0;i<16;i++){
      int n = tid + i*512;
      float den = fmaxf(sqrtf(ssb[n]), 1e-8f) * kn;
      float lg = beta * numb[n] / den;
      lreg[i] = lg;
      lmax = fmaxf(lmax, lg);
    }
    #pragma unroll
    for (int o=32;o;o>>=1) lmax = fmaxf(lmax, __shfl_xor(lmax, o));
    if (lane==0) wred[0][wid] = lmax;
    __syncthreads();
    lmax = wred[0][0];
    #pragma unroll
    for (int w=1;w<8;w++) lmax = fmaxf(lmax, wred[0][w]);
    float lsum = 0.f;
    #pragma unroll
    for (int i=0;i<16;i++){ lreg[i] = __expf(lreg[i]-lmax); lsum += lreg[i]; }
    #pragma unroll
    for (int o=32;o;o>>=1) lsum += __shfl_xor(lsum, o);
    if (lane==0) wred[1][wid] = lsum;
    __syncthreads();
    lsum = 0.f;
    #pragma unroll
    for (int w=0;w<8;w++) lsum += wred[1][w];
    float inv = 1.0f/lsum;
    #pragma unroll
    for (int i=0;i<16;i++){
      int n = tid + i*512;
      buf[n] = g*lreg[i]*inv + (1.0f-g)*wprev[n];
    }
    __syncthreads();   // neighbors must see wg
    float psum = 0.f;
    #pragma unroll
    for (int i=0;i<16;i++){
      int n = tid + i*512;
      float wm = buf[(n-1)&(NN-1)];
      float w0 = buf[n];
      float wp = buf[(n+1)&(NN-1)];
      float wt = s0*wm + s1*w0 + s2*wp;
      float p = __expf(gamma*__logf(wt));
      wfin[i] = p; psum += p;
    }
    #pragma unroll
    for (int o=32;o;o>>=1) psum += __shfl_xor(psum, o);
    if (lane==0) wred[2][wid] = psum;
    __syncthreads();
    psum = 0.f;
    #pragma unroll
    for (int w=0;w<8;w++) psum += wred[2][w];
    float invp = 1.0f/(psum + 1e-16f);
    #pragma unroll
    for (int i=0;i<16;i++){ wfin[i] *= invp; wo[tid + i*512] = wfin[i]; }
  }
  if (role == 0) return;

  // ----- chain 2: head-1 read; ww0 = wfin (same n<->thread mapping) -----
  {
    const float* pb = OUT9 + (size_t)b*NN;
    const float* wp = pwr + S + (size_t)b*NN;
    float* wo = WR1 + (size_t)b*NN;
    const float* sc = scal + ((size_t)2*BB + b)*8;
    float beta=sc[0], g=sc[1], s0=sc[2], s1=sc[3], s2=sc[4], gamma=sc[5], kn=sc[6];
    const float* sc3 = scal + ((size_t)3*BB + b)*8;
    float akr1 = sc3[0], aa = sc3[1];
    float lreg[16];
    float lmax = -1e30f;
    #pragma unroll
    for (int i=0;i<16;i++){
      int n = tid + i*512;
      float ss = pb[2*S+n], t3 = pb[3*S+n], t4 = pb[4*S+n];
      float t5 = pb[5*S+n], t6 = pb[6*S+n], t7 = pb[7*S+n], t8 = pb[8*S+n];
      float w = wfin[i];
      float num  = t3 + w*(akr1 - t4);
      float n1sq = ss + 2.0f*w*(t7 - t5) + w*w*(t6 + aa - 2.0f*t8);
      float nrm = sqrtf(fmaxf(n1sq, 0.f));
      float lg = beta * num / (fmaxf(nrm, 1e-8f) * kn);
      lreg[i] = lg;
      lmax = fmaxf(lmax, lg);
    }
    #pragma unroll
    for (int o=32;o;o>>=1) lmax = fmaxf(lmax, __shfl_xor(lmax, o));
    if (lane==0) wred[3][wid] = lmax;
    __syncthreads();
    lmax = wred[3][0];
    #pragma unroll
    for (int w=1;w<8;w++) lmax = fmaxf(lmax, wred[3][w]);
    float lsum = 0.f;
    #pragma unroll
    for (int i=0;i<16;i++){ lreg[i] = __expf(lreg[i]-lmax); lsum += lreg[i]; }
    #pragma unroll
    for (int o=32;o;o>>=1) lsum += __shfl_xor(lsum, o);
    if (lane==0) wred[4][wid] = lsum;
    __syncthreads();
    lsum = 0.f;
    #pragma unroll
    for (int w=0;w<8;w++) lsum += wred[4][w];
    float inv = 1.0f/lsum;
    #pragma unroll
    for (int i=0;i<16;i++){
      int n = tid + i*512;
      buf[n] = g*lreg[i]*inv + (1.0f-g)*wp[n];
    }
    __syncthreads();
    float psum = 0.f;
    float wt_loc[16];
    #pragma unroll
    for (int i=0;i<16;i++){
      int n = tid + i*512;
      float wm = buf[(n-1)&(NN-1)];
      float w0 = buf[n];
      float wpv = buf[(n+1)&(NN-1)];
      float wt = s0*wm + s1*w0 + s2*wpv;
      float p = __expf(gamma*__logf(wt));
      wt_loc[i] = p; psum += p;
    }
    #pragma unroll
    for (int o=32;o;o>>=1) psum += __shfl_xor(psum, o);
    if (lane==0) wred[5][wid] = psum;
    __syncthreads();
    psum = 0.f;
    #pragma unroll
    for (int w=0;w<8;w++) psum += wred[5][w];
    float invp = 1.0f/(psum + 1e-16f);
    #pragma unroll
    for (int i=0;i<16;i++) wo[tid + i*512] = wt_loc[i]*invp;
  }
}

// ---------- 6. pass F (XCD-affine): 3 weighted row-sums + w2 ----------
__global__ __launch_bounds__(256) void k_passF(
    const float* __restrict__ mem, const float* __restrict__ wr0,
    const float* __restrict__ wr1, const float* __restrict__ ww0,
    float* __restrict__ part)
{
  int l = blockIdx.x;
  int xcd = l & 7, i = l >> 3;
  int b = xcd*8 + (i >> 5);
  int chunk = i & 31;
  int tid = threadIdx.x, ty = tid>>5, lane = tid&31;
  float4 a0 = {0.f,0.f,0.f,0.f}, a1 = a0, a2 = a0;
  float w2 = 0.f;
  for (int it=0; it<32; ++it){
    int n = chunk*256 + it*8 + ty;
    size_t p = (size_t)b*NN + n;
    const float4* row = (const float4*)(mem + p*MM);
    float4 v = row[lane];
    float w0r = wr0[p], w1r = wr1[p], wwr = ww0[p];
    float w12 = w1r*wwr;
    a0.x += w0r*v.x; a0.y += w0r*v.y; a0.z += w0r*v.z; a0.w += w0r*v.w;
    a1.x += w1r*v.x; a1.y += w1r*v.y; a1.z += w1r*v.z; a1.w += w1r*v.w;
    a2.x += w12*v.x; a2.y += w12*v.y; a2.z += w12*v.z; a2.w += w12*v.w;
    if (lane==0) w2 += w12;
  }
  __shared__ float4 sred[256];
  __shared__ float w2s[8];
  float* prow = part + (size_t)(b*CHUNKS + chunk)*PROW;
  float4 accs[3] = {a0,a1,a2};
  #pragma unroll
  for (int q=0;q<3;q++){
    sred[tid] = accs[q];
    __syncthreads();
    if (ty == 0){
      float4 s = {0.f,0.f,0.f,0.f};
      #pragma unroll
      for (int r=0;r<8;r++){
        float4 t = sred[r*32 + lane];
        s.x += t.x; s.y += t.y; s.z += t.z; s.w += t.w;
      }
      ((float4*)(prow + q*MM))[lane] = s;
    }
    __syncthreads();
  }
  if (lane==0) w2s[ty] = w2;
  __syncthreads();
  if (tid==0){
    float s = 0.f;
    #pragma unroll
    for (int r=0;r<8;r++) s += w2s[r];
    prow[384] = s;
  }
}

// ---------- 7. tail (XCD-affine): reduce partials + fc + sigmoid ----------
__global__ __launch_bounds__(256) void k_tail(
    const float* __restrict__ part, const float* __restrict__ COEF8,
    const float* __restrict__ fcW, const float* __restrict__ fcb,
    float* __restrict__ out)
{
  int l = blockIdx.x;
  int b = (l & 7)*8 + (l >> 3);
  int tid = threadIdx.x;
  __shared__ float s_lds[384];
  __shared__ float inp2[256];
  __shared__ float w2sh;
  const float* pbase = part + (size_t)b*CHUNKS*PROW;
  for (int idx=tid; idx<384; idx+=256){
    float s = 0.f;
    for (int c=0;c<CHUNKS;c++) s += pbase[(size_t)c*PROW + idx];
    s_lds[idx] = s;
  }
  if (tid == 0){
    float w = 0.f;
    for (int c=0;c<CHUNKS;c++) w += pbase[(size_t)c*PROW + 384];
    w2sh = w;
  }
  __syncthreads();
  if (tid < 128){
    int m = tid;
    float e = COEF8[((size_t)b*MM + m)*8 + 4];
    float a = COEF8[((size_t)b*MM + m)*8 + 6];
    inp2[m] = s_lds[m];
    inp2[MM + m] = s_lds[MM + m] - e*s_lds[2*MM + m] + w2sh*a;
  }
  __syncthreads();
  if (tid < 128){
    int o = tid;
    float acc = fcb[o];
    const float4* wrow = (const float4*)(fcW + (size_t)o*(2*MM));
    const float4* i2 = (const float4*)inp2;
    #pragma unroll 8
    for (int k4=0; k4<64; ++k4){
      float4 w = wrow[k4];
      float4 v = i2[k4];
      acc += w.x*v.x + w.y*v.y + w.z*v.z + w.w*v.w;
    }
    out[(size_t)b*OUTN + o] = sigf(acc);
  }
}

extern "C" void kernel_launch(void* const* d_in, const int* in_sizes, int n_in,
                              void* d_out, int out_size, void* d_ws, size_t ws_size,
                              hipStream_t stream) {
  const float* x   = (const float*)d_in[0];
  const float* pr  = (const float*)d_in[1];
  const float* h0  = (const float*)d_in[2];
  const float* c0  = (const float*)d_in[3];
  const float* pwr = (const float*)d_in[4];
  const float* pww = (const float*)d_in[5];
  const float* mem = (const float*)d_in[6];
  const float* Wih = (const float*)d_in[7];
  const float* Whh = (const float*)d_in[8];
  const float* bih = (const float*)d_in[9];
  const float* bhh = (const float*)d_in[10];
  const float* Wr  = (const float*)d_in[11];
  const float* br  = (const float*)d_in[12];
  const float* Ww  = (const float*)d_in[13];
  const float* bw  = (const float*)d_in[14];
  const float* fcW = (const float*)d_in[15];
  const float* fcb = (const float*)d_in[16];
  float* out = (float*)d_out;

  float* ws = (float*)d_ws;
  size_t off = 0;
  auto alloc = [&](size_t n){ float* p = ws + off; off += n; return p; };
  const size_t S = (size_t)BB*NN;
  float* GPART = alloc((size_t)4*BB*JTOT);
  float* RPART = alloc((size_t)4*BB*RSTR);
  float* COEF8 = alloc((size_t)BB*MM*8);
  float* SCAL  = alloc((size_t)4*BB*8);
  float* OUT9  = alloc(9*S);
  float* WR0   = alloc(S);
  float* WW0   = alloc(S);     // must stay adjacent to WR0
  float* WR1   = alloc(S);
  float* PART  = alloc((size_t)BB*CHUNKS*PROW);
  (void)ws_size; (void)in_sizes; (void)n_in; (void)out_size; (void)WW0;

  k_lstm_split<<<dim3(64,4), 128, 0, stream>>>(x, pr, h0, Wih, Whh, GPART);
  k_head_split<<<dim3(21,4), 128, 0, stream>>>(GPART, bih, bhh, c0, Wr, Ww, RPART);
  k_params<<<BB, 256, 0, stream>>>(RPART, br, bw, COEF8, SCAL);
  k_passA<<<CHUNKS*BB, 256, 0, stream>>>(mem, COEF8, OUT9);
  k_addr<<<2*BB, 512, 0, stream>>>(OUT9, SCAL, pwr, pww, WR0, WR1);
  k_passF<<<CHUNKS*BB, 256, 0, stream>>>(mem, WR0, WR1, WW0, PART);
  k_tail<<<BB, 256, 0, stream>>>(PART, COEF8, fcW, fcb, out);
}

// Round 11
// 262.003 us; speedup vs baseline: 1.8852x; 1.8852x over previous
//
#include <hip/hip_runtime.h>

#define BB 64
#define NN 8192
#define MM 128
#define HH 512
#define KLSTM 896   // 384 (x|pr0|pr1) + 512 (h0)
#define JTOT 2048
#define COLS 658    // 134 (ro0) + 390 (wo0) + 134 (ro1)
#define OUTN 128
#define CHUNKS 32   // 8192/32 = 256 rows per chunk
#define PROW 388    // PART row stride
#define RSTR 672    // RPART col stride (21 tiles * 32)

__device__ __forceinline__ float sigf(float x){ return 1.0f/(1.0f+__expf(-x)); }
__device__ __forceinline__ float tanhf_f(float x){ return 1.0f - 2.0f/(__expf(2.0f*x)+1.0f); }
__device__ __forceinline__ float softplusf_(float x){ return (x>20.0f)? x : log1pf(expf(x)); }
__device__ __forceinline__ unsigned short bf16rne(float f){
  unsigned int u = __float_as_uint(f);
  u += 0x7FFFu + ((u >> 16) & 1u);
  return (unsigned short)(u >> 16);
}

// ---------- 1. LSTM gemm, 4-way k-split: GPART[ks][b][j] ----------
__global__ __launch_bounds__(128) void k_lstm_split(
    const float* __restrict__ x, const float* __restrict__ pr,
    const float* __restrict__ h0, const float* __restrict__ Wih,
    const float* __restrict__ Whh, float* __restrict__ GPART)
{
  __shared__ float a_s[64][68];   // [kk][b]
  __shared__ float w_s[64][36];   // [kk][j]
  int tid = threadIdx.x;
  int jt = blockIdx.x, ks = blockIdx.y;
  int jbase = jt*32;
  int cbeg = (ks<2)? ks*4 : 8 + (ks-2)*3;   // chunks 4,4,3,3 of 64k
  int cend = (ks<2)? cbeg+4 : cbeg+3;
  int jq = tid & 7, bq = tid >> 3;          // jq 0..7 (4j), bq 0..15 (4b)
  float4 acc0={0,0,0,0}, acc1={0,0,0,0}, acc2={0,0,0,0}, acc3={0,0,0,0};
  for (int c=cbeg; c<cend; ++c){
    int kc = c*64;
    __syncthreads();
    #pragma unroll
    for (int i=0;i<32;i++){
      int idx = tid + i*128;
      int kk = idx & 63, p = idx >> 6;
      int kg = kc + kk;
      float iv;
      if (kg < 128)      iv = x[p*128 + kg];
      else if (kg < 256) iv = pr[p*MM + (kg-128)];
      else if (kg < 384) iv = pr[BB*MM + p*MM + (kg-256)];
      else               iv = h0[p*HH + (kg-384)];
      a_s[kk][p] = iv;
    }
    #pragma unroll
    for (int i=0;i<16;i++){
      int idx = tid + i*128;
      int kk = idx & 63, j = idx >> 6;
      int kg = kc + kk;
      int jj = jbase + j;
      float wv = (kg < 384) ? Wih[(size_t)jj*384 + kg]
                            : Whh[(size_t)jj*512 + (kg-384)];
      w_s[kk][j] = wv;
    }
    __syncthreads();
    #pragma unroll 4
    for (int kk=0; kk<64; ++kk){
      float4 av = *(const float4*)&a_s[kk][bq*4];
      float4 wv = *(const float4*)&w_s[kk][jq*4];
      acc0.x += av.x*wv.x; acc0.y += av.x*wv.y; acc0.z += av.x*wv.z; acc0.w += av.x*wv.w;
      acc1.x += av.y*wv.x; acc1.y += av.y*wv.y; acc1.z += av.y*wv.z; acc1.w += av.y*wv.w;
      acc2.x += av.z*wv.x; acc2.y += av.z*wv.y; acc2.z += av.z*wv.z; acc2.w += av.z*wv.w;
      acc3.x += av.w*wv.x; acc3.y += av.w*wv.y; acc3.z += av.w*wv.z; acc3.w += av.w*wv.w;
    }
  }
  size_t base = (size_t)ks*BB*JTOT;
  int col = jbase + jq*4;
  *(float4*)&GPART[base + (size_t)(bq*4+0)*JTOT + col] = acc0;
  *(float4*)&GPART[base + (size_t)(bq*4+1)*JTOT + col] = acc1;
  *(float4*)&GPART[base + (size_t)(bq*4+2)*JTOT + col] = acc2;
  *(float4*)&GPART[base + (size_t)(bq*4+3)*JTOT + col] = acc3;
}

// ---------- 2. reduce gate partials + LSTM activation -> CTRL ----------
__global__ void k_ctrl(const float* __restrict__ GPART, const float* __restrict__ bih,
                       const float* __restrict__ bhh, const float* __restrict__ c0,
                       float* __restrict__ CTRL)
{
  int idx = blockIdx.x*256 + threadIdx.x;
  if (idx >= BB*HH) return;
  int b = idx >> 9, h = idx & 511;
  float g0 = bih[h]        + bhh[h];
  float g1 = bih[HH+h]     + bhh[HH+h];
  float g2 = bih[2*HH+h]   + bhh[2*HH+h];
  float g3 = bih[3*HH+h]   + bhh[3*HH+h];
  #pragma unroll
  for (int ks=0; ks<4; ++ks){
    const float* gp = GPART + ((size_t)ks*BB + b)*JTOT;
    g0 += gp[h]; g1 += gp[HH+h]; g2 += gp[2*HH+h]; g3 += gp[3*HH+h];
  }
  float i_ = sigf(g0), f_ = sigf(g1), gg = tanhf_f(g2), o_ = sigf(g3);
  CTRL[idx] = o_*tanhf_f(f_*c0[idx] + i_*gg);
}

// ---------- 3. head gemm, 4-way k-split: RPART[ks][b][col] ----------
__global__ __launch_bounds__(128) void k_head_split(
    const float* __restrict__ CTRL, const float* __restrict__ Wr,
    const float* __restrict__ Ww, float* __restrict__ RPART)
{
  __shared__ float c_s[64][68];
  __shared__ float w_s[64][36];
  int tid = threadIdx.x;
  int ct = blockIdx.x, ks = blockIdx.y;
  int cbase = ct*32;
  int jq = tid & 7, bq = tid >> 3;
  float4 acc0={0,0,0,0}, acc1={0,0,0,0}, acc2={0,0,0,0}, acc3={0,0,0,0};
  for (int cc=0; cc<2; ++cc){
    int kc = ks*128 + cc*64;
    __syncthreads();
    #pragma unroll
    for (int i=0;i<32;i++){
      int idx = tid + i*128;
      int kk = idx & 63, p = idx >> 6;
      c_s[kk][p] = CTRL[(size_t)p*HH + kc + kk];
    }
    #pragma unroll
    for (int i=0;i<16;i++){
      int idx = tid + i*128;
      int kk = idx & 63, j = idx >> 6;
      int col = cbase + j;
      int h = kc + kk;
      float wv = 0.0f;
      if (col < 134)       wv = Wr[(size_t)col*HH + h];
      else if (col < 524)  wv = Ww[(size_t)(col-134)*HH + h];
      else if (col < COLS) wv = Wr[(size_t)(134 + col-524)*HH + h];
      w_s[kk][j] = wv;
    }
    __syncthreads();
    #pragma unroll 4
    for (int kk=0; kk<64; ++kk){
      float4 av = *(const float4*)&c_s[kk][bq*4];
      float4 wv = *(const float4*)&w_s[kk][jq*4];
      acc0.x += av.x*wv.x; acc0.y += av.x*wv.y; acc0.z += av.x*wv.z; acc0.w += av.x*wv.w;
      acc1.x += av.y*wv.x; acc1.y += av.y*wv.y; acc1.z += av.y*wv.z; acc1.w += av.y*wv.w;
      acc2.x += av.z*wv.x; acc2.y += av.z*wv.y; acc2.z += av.z*wv.z; acc2.w += av.z*wv.w;
      acc3.x += av.w*wv.x; acc3.y += av.w*wv.y; acc3.z += av.w*wv.z; acc3.w += av.w*wv.w;
    }
  }
  size_t base = (size_t)ks*BB*RSTR;
  int col = cbase + jq*4;
  *(float4*)&RPART[base + (size_t)(bq*4+0)*RSTR + col] = acc0;
  *(float4*)&RPART[base + (size_t)(bq*4+1)*RSTR + col] = acc1;
  *(float4*)&RPART[base + (size_t)(bq*4+2)*RSTR + col] = acc2;
  *(float4*)&RPART[base + (size_t)(bq*4+3)*RSTR + col] = acc3;
}

// ---------- 4. params: reduce RPART(+bias) -> COEF8[b][m][8], SCAL ----------
__global__ __launch_bounds__(256) void k_params(
    const float* __restrict__ RPART, const float* __restrict__ br,
    const float* __restrict__ bw, float* __restrict__ COEF8,
    float* __restrict__ scal)
{
  int b = blockIdx.x, tid = threadIdx.x;
  __shared__ float ro[RSTR];
  __shared__ float wred[2][5];
  for (int idx=tid; idx<COLS; idx+=256){
    float s = (idx<134)? br[idx] : (idx<524)? bw[idx-134] : br[134 + idx-524];
    #pragma unroll
    for (int ks=0; ks<4; ++ks) s += RPART[((size_t)ks*BB + b)*RSTR + idx];
    ro[idx] = s;
  }
  __syncthreads();
  int m = tid & 127;
  float k0 = ro[m], kw = ro[134+m], k1 = ro[524+m];
  float e  = sigf(ro[268+m]);
  float a  = ro[396+m];
  if (tid < 128){
    float* c8 = COEF8 + ((size_t)b*MM + m)*8;
    *(float4*)c8     = make_float4(k0, kw, k1, e*k1);
    *(float4*)(c8+4) = make_float4(e, e*e, a, a*e);
  }
  float r0=k0*k0, r1=kw*kw, r2=k1*k1, r3=a*k1, r4=a*a;
  #pragma unroll
  for (int off=32; off; off>>=1){
    r0 += __shfl_xor(r0, off);
    r1 += __shfl_xor(r1, off);
    r2 += __shfl_xor(r2, off);
    r3 += __shfl_xor(r3, off);
    r4 += __shfl_xor(r4, off);
  }
  if (tid < 128 && (tid & 63) == 0){
    int w = tid >> 6;
    wred[w][0]=r0; wred[w][1]=r1; wred[w][2]=r2; wred[w][3]=r3; wred[w][4]=r4;
  }
  __syncthreads();
  if (tid < 3){
    float knsq = wred[0][tid] + wred[1][tid];
    float kn = fmaxf(sqrtf(knsq), 1e-8f);
    int base = (tid==0)? 0 : (tid==1)? 134 : 524;
    float beta  = softplusf_(ro[base+128]);
    float g     = sigf(ro[base+129]);
    float s0r = ro[base+130], s1r = ro[base+131], s2r = ro[base+132];
    float mx = fmaxf(s0r, fmaxf(s1r, s2r));
    float es0 = __expf(s0r-mx), es1 = __expf(s1r-mx), es2 = __expf(s2r-mx);
    float es = es0+es1+es2;
    float gamma = 1.0f + softplusf_(ro[base+133]);
    float* sc = scal + ((size_t)tid*BB + b)*8;
    sc[0]=beta; sc[1]=g; sc[2]=es0/es; sc[3]=es1/es; sc[4]=es2/es; sc[5]=gamma; sc[6]=kn;
  }
  if (tid == 3) scal[((size_t)3*BB + b)*8 + 0] = wred[0][3] + wred[1][3];  // a.kr1
  if (tid == 4) scal[((size_t)3*BB + b)*8 + 1] = wred[0][4] + wred[1][4];  // a.a
}

// ---------- 5. pass A: XCD-affine; LDS transpose; 9 per-row scalars; emits bf16 copy ----------
__global__ __launch_bounds__(256) void k_passA(
    const float* __restrict__ mem, const float* __restrict__ COEF8,
    float* __restrict__ OUT9, unsigned short* __restrict__ MEMB)
{
  const size_t S = (size_t)BB*NN;
  int l = blockIdx.x;
  int xcd = l & 7, i = l >> 3;            // i in [0,256)
  int b = xcd*8 + (i >> 5);
  int chunk = i & 31;
  int tid = threadIdx.x;
  __shared__ float vtile[32][257];
  const float4* cb = (const float4*)(COEF8 + (size_t)b*MM*8);  // wave-uniform -> s_load
  int rowbase = chunk*256;
  float acc[9];
  #pragma unroll
  for (int q=0;q<9;q++) acc[q] = 0.f;
  for (int kc=0; kc<4; ++kc){
    __syncthreads();
    #pragma unroll
    for (int ii=0;ii<8;ii++){
      int f = tid + ii*256;
      int r = f >> 3, k4 = f & 7;
      size_t eoff = ((size_t)b*NN + rowbase + r)*MM + kc*32 + k4*4;
      float4 v = *(const float4*)(mem + eoff);
      vtile[k4*4+0][r] = v.x;
      vtile[k4*4+1][r] = v.y;
      vtile[k4*4+2][r] = v.z;
      vtile[k4*4+3][r] = v.w;
      ushort4 h;
      h.x = bf16rne(v.x); h.y = bf16rne(v.y); h.z = bf16rne(v.z); h.w = bf16rne(v.w);
      *(ushort4*)(MEMB + eoff) = h;
    }
    __syncthreads();
    #pragma unroll
    for (int kk=0; kk<32; ++kk){
      int kg = kc*32 + kk;
      float4 cA = cb[kg*2];
      float4 cB = cb[kg*2+1];
      float v  = vtile[kk][tid];
      float vv = v*v;
      acc[0] += v*cA.x;  acc[1] += v*cA.y;  acc[2] += vv;
      acc[3] += v*cA.z;  acc[4] += v*cA.w;
      acc[5] += vv*cB.x; acc[6] += vv*cB.y;
      acc[7] += v*cB.z;  acc[8] += v*cB.w;
    }
  }
  size_t p = (size_t)b*NN + rowbase + tid;
  #pragma unroll
  for (int q=0;q<9;q++) OUT9[(size_t)q*S + p] = acc[q];
}

// ---------- 6. fused addressing (512 thr, XCD-affine), wave-shuffle reductions ----------
__global__ __launch_bounds__(512) void k_addr(
    const float* __restrict__ OUT9, const float* __restrict__ scal,
    const float* __restrict__ pwr, const float* __restrict__ pww,
    float* __restrict__ WR0 /* +S = WW0 */, float* __restrict__ WR1)
{
  const size_t S = (size_t)BB*NN;
  int l = blockIdx.x;
  int xcd = l & 7, j = l >> 3;            // j in [0,16)
  int role = j >> 3;
  int b = xcd*8 + (j & 7);
  int tid = threadIdx.x;
  int lane = tid & 63, wid = tid >> 6;    // 8 waves
  __shared__ float buf[NN];
  __shared__ float wred[6][8];
  float wfin[16];

  // ----- chain 1: head-0, which = role -----
  {
    const float* numb = OUT9 + (size_t)role*S + (size_t)b*NN;
    const float* ssb  = OUT9 + 2*S + (size_t)b*NN;
    const float* wprev = ((role==0)? pwr : pww) + (size_t)b*NN;
    float* wo = WR0 + (size_t)role*S + (size_t)b*NN;
    const float* sc = scal + ((size_t)role*BB + b)*8;
    float beta=sc[0], g=sc[1], s0=sc[2], s1=sc[3], s2=sc[4], gamma=sc[5], kn=sc[6];
    float lreg[16];
    float lmax = -1e30f;
    #pragma unroll
    for (int i=0;i<16;i++){
      int n = tid + i*512;
      float den = fmaxf(sqrtf(ssb[n]), 1e-8f) * kn;
      float lg = beta * numb[n] / den;
      lreg[i] = lg;
      lmax = fmaxf(lmax, lg);
    }
    #pragma unroll
    for (int o=32;o;o>>=1) lmax = fmaxf(lmax, __shfl_xor(lmax, o));
    if (lane==0) wred[0][wid] = lmax;
    __syncthreads();
    lmax = wred[0][0];
    #pragma unroll
    for (int w=1;w<8;w++) lmax = fmaxf(lmax, wred[0][w]);
    float lsum = 0.f;
    #pragma unroll
    for (int i=0;i<16;i++){ lreg[i] = __expf(lreg[i]-lmax); lsum += lreg[i]; }
    #pragma unroll
    for (int o=32;o;o>>=1) lsum += __shfl_xor(lsum, o);
    if (lane==0) wred[1][wid] = lsum;
    __syncthreads();
    lsum = 0.f;
    #pragma unroll
    for (int w=0;w<8;w++) lsum += wred[1][w];
    float inv = 1.0f/lsum;
    #pragma unroll
    for (int i=0;i<16;i++){
      int n = tid + i*512;
      buf[n] = g*lreg[i]*inv + (1.0f-g)*wprev[n];
    }
    __syncthreads();   // neighbors must see wg
    float psum = 0.f;
    #pragma unroll
    for (int i=0;i<16;i++){
      int n = tid + i*512;
      float wm = buf[(n-1)&(NN-1)];
      float w0 = buf[n];
      float wp = buf[(n+1)&(NN-1)];
      float wt = s0*wm + s1*w0 + s2*wp;
      float p = __expf(gamma*__logf(wt));
      wfin[i] = p; psum += p;
    }
    #pragma unroll
    for (int o=32;o;o>>=1) psum += __shfl_xor(psum, o);
    if (lane==0) wred[2][wid] = psum;
    __syncthreads();
    psum = 0.f;
    #pragma unroll
    for (int w=0;w<8;w++) psum += wred[2][w];
    float invp = 1.0f/(psum + 1e-16f);
    #pragma unroll
    for (int i=0;i<16;i++){ wfin[i] *= invp; wo[tid + i*512] = wfin[i]; }
  }
  if (role == 0) return;

  // ----- chain 2: head-1 read; ww0 = wfin (same n<->thread mapping) -----
  {
    const float* pb = OUT9 + (size_t)b*NN;
    const float* wp = pwr + S + (size_t)b*NN;
    float* wo = WR1 + (size_t)b*NN;
    const float* sc = scal + ((size_t)2*BB + b)*8;
    float beta=sc[0], g=sc[1], s0=sc[2], s1=sc[3], s2=sc[4], gamma=sc[5], kn=sc[6];
    const float* sc3 = scal + ((size_t)3*BB + b)*8;
    float akr1 = sc3[0], aa = sc3[1];
    float lreg[16];
    float lmax = -1e30f;
    #pragma unroll
    for (int i=0;i<16;i++){
      int n = tid + i*512;
      float ss = pb[2*S+n], t3 = pb[3*S+n], t4 = pb[4*S+n];
      float t5 = pb[5*S+n], t6 = pb[6*S+n], t7 = pb[7*S+n], t8 = pb[8*S+n];
      float w = wfin[i];
      float num  = t3 + w*(akr1 - t4);
      float n1sq = ss + 2.0f*w*(t7 - t5) + w*w*(t6 + aa - 2.0f*t8);
      float nrm = sqrtf(fmaxf(n1sq, 0.f));
      float lg = beta * num / (fmaxf(nrm, 1e-8f) * kn);
      lreg[i] = lg;
      lmax = fmaxf(lmax, lg);
    }
    #pragma unroll
    for (int o=32;o;o>>=1) lmax = fmaxf(lmax, __shfl_xor(lmax, o));
    if (lane==0) wred[3][wid] = lmax;
    __syncthreads();
    lmax = wred[3][0];
    #pragma unroll
    for (int w=1;w<8;w++) lmax = fmaxf(lmax, wred[3][w]);
    float lsum = 0.f;
    #pragma unroll
    for (int i=0;i<16;i++){ lreg[i] = __expf(lreg[i]-lmax); lsum += lreg[i]; }
    #pragma unroll
    for (int o=32;o;o>>=1) lsum += __shfl_xor(lsum, o);
    if (lane==0) wred[4][wid] = lsum;
    __syncthreads();
    lsum = 0.f;
    #pragma unroll
    for (int w=0;w<8;w++) lsum += wred[4][w];
    float inv = 1.0f/lsum;
    #pragma unroll
    for (int i=0;i<16;i++){
      int n = tid + i*512;
      buf[n] = g*lreg[i]*inv + (1.0f-g)*wp[n];
    }
    __syncthreads();
    float psum = 0.f;
    float wt_loc[16];
    #pragma unroll
    for (int i=0;i<16;i++){
      int n = tid + i*512;
      float wm = buf[(n-1)&(NN-1)];
      float w0 = buf[n];
      float wpv = buf[(n+1)&(NN-1)];
      float wt = s0*wm + s1*w0 + s2*wpv;
      float p = __expf(gamma*__logf(wt));
      wt_loc[i] = p; psum += p;
    }
    #pragma unroll
    for (int o=32;o;o>>=1) psum += __shfl_xor(psum, o);
    if (lane==0) wred[5][wid] = psum;
    __syncthreads();
    psum = 0.f;
    #pragma unroll
    for (int w=0;w<8;w++) psum += wred[5][w];
    float invp = 1.0f/(psum + 1e-16f);
    #pragma unroll
    for (int i=0;i<16;i++) wo[tid + i*512] = wt_loc[i]*invp;
  }
}

// ---------- 7. pass F (bf16 copy, XCD-affine): 3 weighted row-sums + w2 ----------
__global__ __launch_bounds__(256) void k_passF(
    const unsigned short* __restrict__ memb, const float* __restrict__ wr0,
    const float* __restrict__ wr1, const float* __restrict__ ww0,
    float* __restrict__ part)
{
  int l = blockIdx.x;
  int xcd = l & 7, i = l >> 3;
  int b = xcd*8 + (i >> 5);
  int chunk = i & 31;
  int tid = threadIdx.x, ty = tid>>5, lane = tid&31;
  float4 a0 = {0.f,0.f,0.f,0.f}, a1 = a0, a2 = a0;
  float w2 = 0.f;
  for (int it=0; it<32; ++it){
    int n = chunk*256 + it*8 + ty;
    size_t p = (size_t)b*NN + n;
    const uint2* row = (const uint2*)(memb + p*MM);
    uint2 u = row[lane];
    float vx = __uint_as_float(u.x << 16);
    float vy = __uint_as_float(u.x & 0xFFFF0000u);
    float vz = __uint_as_float(u.y << 16);
    float vw = __uint_as_float(u.y & 0xFFFF0000u);
    float w0r = wr0[p], w1r = wr1[p], wwr = ww0[p];
    float w12 = w1r*wwr;
    a0.x += w0r*vx; a0.y += w0r*vy; a0.z += w0r*vz; a0.w += w0r*vw;
    a1.x += w1r*vx; a1.y += w1r*vy; a1.z += w1r*vz; a1.w += w1r*vw;
    a2.x += w12*vx; a2.y += w12*vy; a2.z += w12*vz; a2.w += w12*vw;
    if (lane==0) w2 += w12;
  }
  __shared__ float4 sred[256];
  __shared__ float w2s[8];
  float* prow = part + (size_t)(b*CHUNKS + chunk)*PROW;
  float4 accs[3] = {a0,a1,a2};
  #pragma unroll
  for (int q=0;q<3;q++){
    sred[tid] = accs[q];
    __syncthreads();
    if (ty == 0){
      float4 s = {0.f,0.f,0.f,0.f};
      #pragma unroll
      for (int r=0;r<8;r++){
        float4 t = sred[r*32 + lane];
        s.x += t.x; s.y += t.y; s.z += t.z; s.w += t.w;
      }
      ((float4*)(prow + q*MM))[lane] = s;
    }
    __syncthreads();
  }
  if (lane==0) w2s[ty] = w2;
  __syncthreads();
  if (tid==0){
    float s = 0.f;
    #pragma unroll
    for (int r=0;r<8;r++) s += w2s[r];
    prow[384] = s;
  }
}

// ---------- 8. tail (XCD-affine): reduce partials + fc + sigmoid ----------
__global__ __launch_bounds__(256) void k_tail(
    const float* __restrict__ part, const float* __restrict__ COEF8,
    const float* __restrict__ fcW, const float* __restrict__ fcb,
    float* __restrict__ out)
{
  int l = blockIdx.x;
  int b = (l & 7)*8 + (l >> 3);
  int tid = threadIdx.x;
  __shared__ float s_lds[384];
  __shared__ float inp2[256];
  __shared__ float w2sh;
  const float* pbase = part + (size_t)b*CHUNKS*PROW;
  for (int idx=tid; idx<384; idx+=256){
    float s = 0.f;
    for (int c=0;c<CHUNKS;c++) s += pbase[(size_t)c*PROW + idx];
    s_lds[idx] = s;
  }
  if (tid == 0){
    float w = 0.f;
    for (int c=0;c<CHUNKS;c++) w += pbase[(size_t)c*PROW + 384];
    w2sh = w;
  }
  __syncthreads();
  if (tid < 128){
    int m = tid;
    float e = COEF8[((size_t)b*MM + m)*8 + 4];
    float a = COEF8[((size_t)b*MM + m)*8 + 6];
    inp2[m] = s_lds[m];
    inp2[MM + m] = s_lds[MM + m] - e*s_lds[2*MM + m] + w2sh*a;
  }
  __syncthreads();
  if (tid < 128){
    int o = tid;
    float acc = fcb[o];
    const float4* wrow = (const float4*)(fcW + (size_t)o*(2*MM));
    const float4* i2 = (const float4*)inp2;
    #pragma unroll 8
    for (int k4=0; k4<64; ++k4){
      float4 w = wrow[k4];
      float4 v = i2[k4];
      acc += w.x*v.x + w.y*v.y + w.z*v.z + w.w*v.w;
    }
    out[(size_t)b*OUTN + o] = sigf(acc);
  }
}

extern "C" void kernel_launch(void* const* d_in, const int* in_sizes, int n_in,
                              void* d_out, int out_size, void* d_ws, size_t ws_size,
                              hipStream_t stream) {
  const float* x   = (const float*)d_in[0];
  const float* pr  = (const float*)d_in[1];
  const float* h0  = (const float*)d_in[2];
  const float* c0  = (const float*)d_in[3];
  const float* pwr = (const float*)d_in[4];
  const float* pww = (const float*)d_in[5];
  const float* mem = (const float*)d_in[6];
  const float* Wih = (const float*)d_in[7];
  const float* Whh = (const float*)d_in[8];
  const float* bih = (const float*)d_in[9];
  const float* bhh = (const float*)d_in[10];
  const float* Wr  = (const float*)d_in[11];
  const float* br  = (const float*)d_in[12];
  const float* Ww  = (const float*)d_in[13];
  const float* bw  = (const float*)d_in[14];
  const float* fcW = (const float*)d_in[15];
  const float* fcb = (const float*)d_in[16];
  float* out = (float*)d_out;

  float* ws = (float*)d_ws;
  size_t off = 0;
  auto alloc = [&](size_t n){ float* p = ws + off; off += n; return p; };
  const size_t S = (size_t)BB*NN;
  float* GPART = alloc((size_t)4*BB*JTOT);
  float* CTRL  = alloc((size_t)BB*HH);
  float* RPART = alloc((size_t)4*BB*RSTR);
  float* COEF8 = alloc((size_t)BB*MM*8);
  float* SCAL  = alloc((size_t)4*BB*8);
  float* OUT9  = alloc(9*S);
  float* WR0   = alloc(S);
  float* WW0   = alloc(S);     // must stay adjacent to WR0
  float* WR1   = alloc(S);
  float* PART  = alloc((size_t)BB*CHUNKS*PROW);
  float* MEMBf = alloc(S*MM/2);        // 134 MB bf16 copy of mem
  unsigned short* MEMB = (unsigned short*)MEMBf;
  (void)ws_size; (void)in_sizes; (void)n_in; (void)out_size; (void)WW0;

  k_lstm_split<<<dim3(64,4), 128, 0, stream>>>(x, pr, h0, Wih, Whh, GPART);
  k_ctrl<<<(BB*HH+255)/256, 256, 0, stream>>>(GPART, bih, bhh, c0, CTRL);
  k_head_split<<<dim3(21,4), 128, 0, stream>>>(CTRL, Wr, Ww, RPART);
  k_params<<<BB, 256, 0, stream>>>(RPART, br, bw, COEF8, SCAL);
  k_passA<<<CHUNKS*BB, 256, 0, stream>>>(mem, COEF8, OUT9, MEMB);
  k_addr<<<2*BB, 512, 0, stream>>>(OUT9, SCAL, pwr, pww, WR0, WR1);
  k_passF<<<CHUNKS*BB, 256, 0, stream>>>(MEMB, WR0, WR1, WW0, PART);
  k_tail<<<BB, 256, 0, stream>>>(PART, COEF8, fcW, fcb, out);
}

// Round 12
// 233.606 us; speedup vs baseline: 2.1144x; 1.1216x over previous
//
#include <hip/hip_runtime.h>

#define BB 64
#define NN 8192
#define MM 128
#define HH 512
#define KLSTM 896   // 384 (x|pr0|pr1) + 512 (h0)
#define JTOT 2048
#define COLS 658    // 134 (ro0) + 390 (wo0) + 134 (ro1)
#define OUTN 128
#define CHUNKS 32   // 8192/32 = 256 rows per chunk
#define PROW 388    // PART row stride
#define RSTR 672    // RPART col stride (21 tiles * 32)

__device__ __forceinline__ float sigf(float x){ return 1.0f/(1.0f+__expf(-x)); }
__device__ __forceinline__ float tanhf_f(float x){ return 1.0f - 2.0f/(__expf(2.0f*x)+1.0f); }
__device__ __forceinline__ float softplusf_(float x){ return (x>20.0f)? x : log1pf(expf(x)); }

// ---------- 1. LSTM gemm, 4-way k-split: GPART[ks][b][j] ----------
__global__ __launch_bounds__(128) void k_lstm_split(
    const float* __restrict__ x, const float* __restrict__ pr,
    const float* __restrict__ h0, const float* __restrict__ Wih,
    const float* __restrict__ Whh, float* __restrict__ GPART)
{
  __shared__ float a_s[64][68];   // [kk][b]
  __shared__ float w_s[64][36];   // [kk][j]
  int tid = threadIdx.x;
  int jt = blockIdx.x, ks = blockIdx.y;
  int jbase = jt*32;
  int cbeg = (ks<2)? ks*4 : 8 + (ks-2)*3;   // chunks 4,4,3,3 of 64k
  int cend = (ks<2)? cbeg+4 : cbeg+3;
  int jq = tid & 7, bq = tid >> 3;          // jq 0..7 (4j), bq 0..15 (4b)
  float4 acc0={0,0,0,0}, acc1={0,0,0,0}, acc2={0,0,0,0}, acc3={0,0,0,0};
  for (int c=cbeg; c<cend; ++c){
    int kc = c*64;
    __syncthreads();
    #pragma unroll
    for (int i=0;i<32;i++){
      int idx = tid + i*128;
      int kk = idx & 63, p = idx >> 6;
      int kg = kc + kk;
      float iv;
      if (kg < 128)      iv = x[p*128 + kg];
      else if (kg < 256) iv = pr[p*MM + (kg-128)];
      else if (kg < 384) iv = pr[BB*MM + p*MM + (kg-256)];
      else               iv = h0[p*HH + (kg-384)];
      a_s[kk][p] = iv;
    }
    #pragma unroll
    for (int i=0;i<16;i++){
      int idx = tid + i*128;
      int kk = idx & 63, j = idx >> 6;
      int kg = kc + kk;
      int jj = jbase + j;
      float wv = (kg < 384) ? Wih[(size_t)jj*384 + kg]
                            : Whh[(size_t)jj*512 + (kg-384)];
      w_s[kk][j] = wv;
    }
    __syncthreads();
    #pragma unroll 4
    for (int kk=0; kk<64; ++kk){
      float4 av = *(const float4*)&a_s[kk][bq*4];
      float4 wv = *(const float4*)&w_s[kk][jq*4];
      acc0.x += av.x*wv.x; acc0.y += av.x*wv.y; acc0.z += av.x*wv.z; acc0.w += av.x*wv.w;
      acc1.x += av.y*wv.x; acc1.y += av.y*wv.y; acc1.z += av.y*wv.z; acc1.w += av.y*wv.w;
      acc2.x += av.z*wv.x; acc2.y += av.z*wv.y; acc2.z += av.z*wv.z; acc2.w += av.z*wv.w;
      acc3.x += av.w*wv.x; acc3.y += av.w*wv.y; acc3.z += av.w*wv.z; acc3.w += av.w*wv.w;
    }
  }
  size_t base = (size_t)ks*BB*JTOT;
  int col = jbase + jq*4;
  *(float4*)&GPART[base + (size_t)(bq*4+0)*JTOT + col] = acc0;
  *(float4*)&GPART[base + (size_t)(bq*4+1)*JTOT + col] = acc1;
  *(float4*)&GPART[base + (size_t)(bq*4+2)*JTOT + col] = acc2;
  *(float4*)&GPART[base + (size_t)(bq*4+3)*JTOT + col] = acc3;
}

// ---------- 2. reduce gate partials + LSTM activation -> CTRL ----------
__global__ void k_ctrl(const float* __restrict__ GPART, const float* __restrict__ bih,
                       const float* __restrict__ bhh, const float* __restrict__ c0,
                       float* __restrict__ CTRL)
{
  int idx = blockIdx.x*256 + threadIdx.x;
  if (idx >= BB*HH) return;
  int b = idx >> 9, h = idx & 511;
  float g0 = bih[h]        + bhh[h];
  float g1 = bih[HH+h]     + bhh[HH+h];
  float g2 = bih[2*HH+h]   + bhh[2*HH+h];
  float g3 = bih[3*HH+h]   + bhh[3*HH+h];
  #pragma unroll
  for (int ks=0; ks<4; ++ks){
    const float* gp = GPART + ((size_t)ks*BB + b)*JTOT;
    g0 += gp[h]; g1 += gp[HH+h]; g2 += gp[2*HH+h]; g3 += gp[3*HH+h];
  }
  float i_ = sigf(g0), f_ = sigf(g1), gg = tanhf_f(g2), o_ = sigf(g3);
  CTRL[idx] = o_*tanhf_f(f_*c0[idx] + i_*gg);
}

// ---------- 3. head gemm, 4-way k-split: RPART[ks][b][col] ----------
__global__ __launch_bounds__(128) void k_head_split(
    const float* __restrict__ CTRL, const float* __restrict__ Wr,
    const float* __restrict__ Ww, float* __restrict__ RPART)
{
  __shared__ float c_s[64][68];
  __shared__ float w_s[64][36];
  int tid = threadIdx.x;
  int ct = blockIdx.x, ks = blockIdx.y;
  int cbase = ct*32;
  int jq = tid & 7, bq = tid >> 3;
  float4 acc0={0,0,0,0}, acc1={0,0,0,0}, acc2={0,0,0,0}, acc3={0,0,0,0};
  for (int cc=0; cc<2; ++cc){
    int kc = ks*128 + cc*64;
    __syncthreads();
    #pragma unroll
    for (int i=0;i<32;i++){
      int idx = tid + i*128;
      int kk = idx & 63, p = idx >> 6;
      c_s[kk][p] = CTRL[(size_t)p*HH + kc + kk];
    }
    #pragma unroll
    for (int i=0;i<16;i++){
      int idx = tid + i*128;
      int kk = idx & 63, j = idx >> 6;
      int col = cbase + j;
      int h = kc + kk;
      float wv = 0.0f;
      if (col < 134)       wv = Wr[(size_t)col*HH + h];
      else if (col < 524)  wv = Ww[(size_t)(col-134)*HH + h];
      else if (col < COLS) wv = Wr[(size_t)(134 + col-524)*HH + h];
      w_s[kk][j] = wv;
    }
    __syncthreads();
    #pragma unroll 4
    for (int kk=0; kk<64; ++kk){
      float4 av = *(const float4*)&c_s[kk][bq*4];
      float4 wv = *(const float4*)&w_s[kk][jq*4];
      acc0.x += av.x*wv.x; acc0.y += av.x*wv.y; acc0.z += av.x*wv.z; acc0.w += av.x*wv.w;
      acc1.x += av.y*wv.x; acc1.y += av.y*wv.y; acc1.z += av.y*wv.z; acc1.w += av.y*wv.w;
      acc2.x += av.z*wv.x; acc2.y += av.z*wv.y; acc2.z += av.z*wv.z; acc2.w += av.z*wv.w;
      acc3.x += av.w*wv.x; acc3.y += av.w*wv.y; acc3.z += av.w*wv.z; acc3.w += av.w*wv.w;
    }
  }
  size_t base = (size_t)ks*BB*RSTR;
  int col = cbase + jq*4;
  *(float4*)&RPART[base + (size_t)(bq*4+0)*RSTR + col] = acc0;
  *(float4*)&RPART[base + (size_t)(bq*4+1)*RSTR + col] = acc1;
  *(float4*)&RPART[base + (size_t)(bq*4+2)*RSTR + col] = acc2;
  *(float4*)&RPART[base + (size_t)(bq*4+3)*RSTR + col] = acc3;
}

// ---------- 4. params: reduce RPART(+bias) -> COEF8[b][m][8], SCAL ----------
__global__ __launch_bounds__(256) void k_params(
    const float* __restrict__ RPART, const float* __restrict__ br,
    const float* __restrict__ bw, float* __restrict__ COEF8,
    float* __restrict__ scal)
{
  int b = blockIdx.x, tid = threadIdx.x;
  __shared__ float ro[RSTR];
  __shared__ float wred[2][5];
  for (int idx=tid; idx<COLS; idx+=256){
    float s = (idx<134)? br[idx] : (idx<524)? bw[idx-134] : br[134 + idx-524];
    #pragma unroll
    for (int ks=0; ks<4; ++ks) s += RPART[((size_t)ks*BB + b)*RSTR + idx];
    ro[idx] = s;
  }
  __syncthreads();
  int m = tid & 127;
  float k0 = ro[m], kw = ro[134+m], k1 = ro[524+m];
  float e  = sigf(ro[268+m]);
  float a  = ro[396+m];
  if (tid < 128){
    float* c8 = COEF8 + ((size_t)b*MM + m)*8;
    *(float4*)c8     = make_float4(k0, kw, k1, e*k1);
    *(float4*)(c8+4) = make_float4(e, e*e, a, a*e);
  }
  float r0=k0*k0, r1=kw*kw, r2=k1*k1, r3=a*k1, r4=a*a;
  #pragma unroll
  for (int off=32; off; off>>=1){
    r0 += __shfl_xor(r0, off);
    r1 += __shfl_xor(r1, off);
    r2 += __shfl_xor(r2, off);
    r3 += __shfl_xor(r3, off);
    r4 += __shfl_xor(r4, off);
  }
  if (tid < 128 && (tid & 63) == 0){
    int w = tid >> 6;
    wred[w][0]=r0; wred[w][1]=r1; wred[w][2]=r2; wred[w][3]=r3; wred[w][4]=r4;
  }
  __syncthreads();
  if (tid < 3){
    float knsq = wred[0][tid] + wred[1][tid];
    float kn = fmaxf(sqrtf(knsq), 1e-8f);
    int base = (tid==0)? 0 : (tid==1)? 134 : 524;
    float beta  = softplusf_(ro[base+128]);
    float g     = sigf(ro[base+129]);
    float s0r = ro[base+130], s1r = ro[base+131], s2r = ro[base+132];
    float mx = fmaxf(s0r, fmaxf(s1r, s2r));
    float es0 = __expf(s0r-mx), es1 = __expf(s1r-mx), es2 = __expf(s2r-mx);
    float es = es0+es1+es2;
    float gamma = 1.0f + softplusf_(ro[base+133]);
    float* sc = scal + ((size_t)tid*BB + b)*8;
    sc[0]=beta; sc[1]=g; sc[2]=es0/es; sc[3]=es1/es; sc[4]=es2/es; sc[5]=gamma; sc[6]=kn;
  }
  if (tid == 3) scal[((size_t)3*BB + b)*8 + 0] = wred[0][3] + wred[1][3];  // a.kr1
  if (tid == 4) scal[((size_t)3*BB + b)*8 + 1] = wred[0][4] + wred[1][4];  // a.a
}

// ---------- 5. pass A: XCD-affine; LDS transpose; 9 per-row scalars ----------
__global__ __launch_bounds__(256) void k_passA(
    const float* __restrict__ mem, const float* __restrict__ COEF8,
    float* __restrict__ OUT9)
{
  const size_t S = (size_t)BB*NN;
  int l = blockIdx.x;
  int xcd = l & 7, i = l >> 3;            // i in [0,256)
  int b = xcd*8 + (i >> 5);
  int chunk = i & 31;
  int tid = threadIdx.x;
  __shared__ float vtile[32][257];
  const float4* cb = (const float4*)(COEF8 + (size_t)b*MM*8);  // wave-uniform -> s_load
  int rowbase = chunk*256;
  float acc[9];
  #pragma unroll
  for (int q=0;q<9;q++) acc[q] = 0.f;
  for (int kc=0; kc<4; ++kc){
    __syncthreads();
    #pragma unroll
    for (int ii=0;ii<8;ii++){
      int f = tid + ii*256;
      int r = f >> 3, k4 = f & 7;
      float4 v = *(const float4*)(mem + ((size_t)b*NN + rowbase + r)*MM + kc*32 + k4*4);
      vtile[k4*4+0][r] = v.x;
      vtile[k4*4+1][r] = v.y;
      vtile[k4*4+2][r] = v.z;
      vtile[k4*4+3][r] = v.w;
    }
    __syncthreads();
    #pragma unroll
    for (int kk=0; kk<32; ++kk){
      int kg = kc*32 + kk;
      float4 cA = cb[kg*2];
      float4 cB = cb[kg*2+1];
      float v  = vtile[kk][tid];
      float vv = v*v;
      acc[0] += v*cA.x;  acc[1] += v*cA.y;  acc[2] += vv;
      acc[3] += v*cA.z;  acc[4] += v*cA.w;
      acc[5] += vv*cB.x; acc[6] += vv*cB.y;
      acc[7] += v*cB.z;  acc[8] += v*cB.w;
    }
  }
  size_t p = (size_t)b*NN + rowbase + tid;
  #pragma unroll
  for (int q=0;q<9;q++) OUT9[(size_t)q*S + p] = acc[q];
}

// ---------- 6. fused addressing (512 thr, XCD-affine), wave-shuffle reductions ----------
__global__ __launch_bounds__(512) void k_addr(
    const float* __restrict__ OUT9, const float* __restrict__ scal,
    const float* __restrict__ pwr, const float* __restrict__ pww,
    float* __restrict__ WR0 /* +S = WW0 */, float* __restrict__ WR1)
{
  const size_t S = (size_t)BB*NN;
  int l = blockIdx.x;
  int xcd = l & 7, j = l >> 3;            // j in [0,16)
  int role = j >> 3;
  int b = xcd*8 + (j & 7);
  int tid = threadIdx.x;
  int lane = tid & 63, wid = tid >> 6;    // 8 waves
  __shared__ float buf[NN];
  __shared__ float wred[6][8];
  float wfin[16];

  // ----- chain 1: head-0, which = role -----
  {
    const float* numb = OUT9 + (size_t)role*S + (size_t)b*NN;
    const float* ssb  = OUT9 + 2*S + (size_t)b*NN;
    const float* wprev = ((role==0)? pwr : pww) + (size_t)b*NN;
    float* wo = WR0 + (size_t)role*S + (size_t)b*NN;
    const float* sc = scal + ((size_t)role*BB + b)*8;
    float beta=sc[0], g=sc[1], s0=sc[2], s1=sc[3], s2=sc[4], gamma=sc[5], kn=sc[6];
    float lreg[16];
    float lmax = -1e30f;
    #pragma unroll
    for (int i=0;i<16;i++){
      int n = tid + i*512;
      float den = fmaxf(sqrtf(ssb[n]), 1e-8f) * kn;
      float lg = beta * numb[n] / den;
      lreg[i] = lg;
      lmax = fmaxf(lmax, lg);
    }
    #pragma unroll
    for (int o=32;o;o>>=1) lmax = fmaxf(lmax, __shfl_xor(lmax, o));
    if (lane==0) wred[0][wid] = lmax;
    __syncthreads();
    lmax = wred[0][0];
    #pragma unroll
    for (int w=1;w<8;w++) lmax = fmaxf(lmax, wred[0][w]);
    float lsum = 0.f;
    #pragma unroll
    for (int i=0;i<16;i++){ lreg[i] = __expf(lreg[i]-lmax); lsum += lreg[i]; }
    #pragma unroll
    for (int o=32;o;o>>=1) lsum += __shfl_xor(lsum, o);
    if (lane==0) wred[1][wid] = lsum;
    __syncthreads();
    lsum = 0.f;
    #pragma unroll
    for (int w=0;w<8;w++) lsum += wred[1][w];
    float inv = 1.0f/lsum;
    #pragma unroll
    for (int i=0;i<16;i++){
      int n = tid + i*512;
      buf[n] = g*lreg[i]*inv + (1.0f-g)*wprev[n];
    }
    __syncthreads();   // neighbors must see wg
    float psum = 0.f;
    #pragma unroll
    for (int i=0;i<16;i++){
      int n = tid + i*512;
      float wm = buf[(n-1)&(NN-1)];
      float w0 = buf[n];
      float wp = buf[(n+1)&(NN-1)];
      float wt = s0*wm + s1*w0 + s2*wp;
      float p = __expf(gamma*__logf(wt));
      wfin[i] = p; psum += p;
    }
    #pragma unroll
    for (int o=32;o;o>>=1) psum += __shfl_xor(psum, o);
    if (lane==0) wred[2][wid] = psum;
    __syncthreads();
    psum = 0.f;
    #pragma unroll
    for (int w=0;w<8;w++) psum += wred[2][w];
    float invp = 1.0f/(psum + 1e-16f);
    #pragma unroll
    for (int i=0;i<16;i++){ wfin[i] *= invp; wo[tid + i*512] = wfin[i]; }
  }
  if (role == 0) return;

  // ----- chain 2: head-1 read; ww0 = wfin (same n<->thread mapping) -----
  {
    const float* pb = OUT9 + (size_t)b*NN;
    const float* wp = pwr + S + (size_t)b*NN;
    float* wo = WR1 + (size_t)b*NN;
    const float* sc = scal + ((size_t)2*BB + b)*8;
    float beta=sc[0], g=sc[1], s0=sc[2], s1=sc[3], s2=sc[4], gamma=sc[5], kn=sc[6];
    const float* sc3 = scal + ((size_t)3*BB + b)*8;
    float akr1 = sc3[0], aa = sc3[1];
    float lreg[16];
    float lmax = -1e30f;
    #pragma unroll
    for (int i=0;i<16;i++){
      int n = tid + i*512;
      float ss = pb[2*S+n], t3 = pb[3*S+n], t4 = pb[4*S+n];
      float t5 = pb[5*S+n], t6 = pb[6*S+n], t7 = pb[7*S+n], t8 = pb[8*S+n];
      float w = wfin[i];
      float num  = t3 + w*(akr1 - t4);
      float n1sq = ss + 2.0f*w*(t7 - t5) + w*w*(t6 + aa - 2.0f*t8);
      float nrm = sqrtf(fmaxf(n1sq, 0.f));
      float lg = beta * num / (fmaxf(nrm, 1e-8f) * kn);
      lreg[i] = lg;
      lmax = fmaxf(lmax, lg);
    }
    #pragma unroll
    for (int o=32;o;o>>=1) lmax = fmaxf(lmax, __shfl_xor(lmax, o));
    if (lane==0) wred[3][wid] = lmax;
    __syncthreads();
    lmax = wred[3][0];
    #pragma unroll
    for (int w=1;w<8;w++) lmax = fmaxf(lmax, wred[3][w]);
    float lsum = 0.f;
    #pragma unroll
    for (int i=0;i<16;i++){ lreg[i] = __expf(lreg[i]-lmax); lsum += lreg[i]; }
    #pragma unroll
    for (int o=32;o;o>>=1) lsum += __shfl_xor(lsum, o);
    if (lane==0) wred[4][wid] = lsum;
    __syncthreads();
    lsum = 0.f;
    #pragma unroll
    for (int w=0;w<8;w++) lsum += wred[4][w];
    float inv = 1.0f/lsum;
    #pragma unroll
    for (int i=0;i<16;i++){
      int n = tid + i*512;
      buf[n] = g*lreg[i]*inv + (1.0f-g)*wp[n];
    }
    __syncthreads();
    float psum = 0.f;
    float wt_loc[16];
    #pragma unroll
    for (int i=0;i<16;i++){
      int n = tid + i*512;
      float wm = buf[(n-1)&(NN-1)];
      float w0 = buf[n];
      float wpv = buf[(n+1)&(NN-1)];
      float wt = s0*wm + s1*w0 + s2*wpv;
      float p = __expf(gamma*__logf(wt));
      wt_loc[i] = p; psum += p;
    }
    #pragma unroll
    for (int o=32;o;o>>=1) psum += __shfl_xor(psum, o);
    if (lane==0) wred[5][wid] = psum;
    __syncthreads();
    psum = 0.f;
    #pragma unroll
    for (int w=0;w<8;w++) psum += wred[5][w];
    float invp = 1.0f/(psum + 1e-16f);
    #pragma unroll
    for (int i=0;i<16;i++) wo[tid + i*512] = wt_loc[i]*invp;
  }
}

// ---------- 7. pass F (XCD-affine): 3 weighted row-sums + w2 ----------
__global__ __launch_bounds__(256) void k_passF(
    const float* __restrict__ mem, const float* __restrict__ wr0,
    const float* __restrict__ wr1, const float* __restrict__ ww0,
    float* __restrict__ part)
{
  int l = blockIdx.x;
  int xcd = l & 7, i = l >> 3;
  int b = xcd*8 + (i >> 5);
  int chunk = i & 31;
  int tid = threadIdx.x, ty = tid>>5, lane = tid&31;
  float4 a0 = {0.f,0.f,0.f,0.f}, a1 = a0, a2 = a0;
  float w2 = 0.f;
  for (int it=0; it<32; ++it){
    int n = chunk*256 + it*8 + ty;
    size_t p = (size_t)b*NN + n;
    const float4* row = (const float4*)(mem + p*MM);
    float4 v = row[lane];
    float w0r = wr0[p], w1r = wr1[p], wwr = ww0[p];
    float w12 = w1r*wwr;
    a0.x += w0r*v.x; a0.y += w0r*v.y; a0.z += w0r*v.z; a0.w += w0r*v.w;
    a1.x += w1r*v.x; a1.y += w1r*v.y; a1.z += w1r*v.z; a1.w += w1r*v.w;
    a2.x += w12*v.x; a2.y += w12*v.y; a2.z += w12*v.z; a2.w += w12*v.w;
    if (lane==0) w2 += w12;
  }
  __shared__ float4 sred[256];
  __shared__ float w2s[8];
  float* prow = part + (size_t)(b*CHUNKS + chunk)*PROW;
  float4 accs[3] = {a0,a1,a2};
  #pragma unroll
  for (int q=0;q<3;q++){
    sred[tid] = accs[q];
    __syncthreads();
    if (ty == 0){
      float4 s = {0.f,0.f,0.f,0.f};
      #pragma unroll
      for (int r=0;r<8;r++){
        float4 t = sred[r*32 + lane];
        s.x += t.x; s.y += t.y; s.z += t.z; s.w += t.w;
      }
      ((float4*)(prow + q*MM))[lane] = s;
    }
    __syncthreads();
  }
  if (lane==0) w2s[ty] = w2;
  __syncthreads();
  if (tid==0){
    float s = 0.f;
    #pragma unroll
    for (int r=0;r<8;r++) s += w2s[r];
    prow[384] = s;
  }
}

// ---------- 8. tail (XCD-affine): reduce partials + fc + sigmoid ----------
__global__ __launch_bounds__(256) void k_tail(
    const float* __restrict__ part, const float* __restrict__ COEF8,
    const float* __restrict__ fcW, const float* __restrict__ fcb,
    float* __restrict__ out)
{
  int l = blockIdx.x;
  int b = (l & 7)*8 + (l >> 3);
  int tid = threadIdx.x;
  __shared__ float s_lds[384];
  __shared__ float inp2[256];
  __shared__ float w2sh;
  const float* pbase = part + (size_t)b*CHUNKS*PROW;
  for (int idx=tid; idx<384; idx+=256){
    float s = 0.f;
    for (int c=0;c<CHUNKS;c++) s += pbase[(size_t)c*PROW + idx];
    s_lds[idx] = s;
  }
  if (tid == 0){
    float w = 0.f;
    for (int c=0;c<CHUNKS;c++) w += pbase[(size_t)c*PROW + 384];
    w2sh = w;
  }
  __syncthreads();
  if (tid < 128){
    int m = tid;
    float e = COEF8[((size_t)b*MM + m)*8 + 4];
    float a = COEF8[((size_t)b*MM + m)*8 + 6];
    inp2[m] = s_lds[m];
    inp2[MM + m] = s_lds[MM + m] - e*s_lds[2*MM + m] + w2sh*a;
  }
  __syncthreads();
  if (tid < 128){
    int o = tid;
    float acc = fcb[o];
    const float4* wrow = (const float4*)(fcW + (size_t)o*(2*MM));
    const float4* i2 = (const float4*)inp2;
    #pragma unroll 8
    for (int k4=0; k4<64; ++k4){
      float4 w = wrow[k4];
      float4 v = i2[k4];
      acc += w.x*v.x + w.y*v.y + w.z*v.z + w.w*v.w;
    }
    out[(size_t)b*OUTN + o] = sigf(acc);
  }
}

extern "C" void kernel_launch(void* const* d_in, const int* in_sizes, int n_in,
                              void* d_out, int out_size, void* d_ws, size_t ws_size,
                              hipStream_t stream) {
  const float* x   = (const float*)d_in[0];
  const float* pr  = (const float*)d_in[1];
  const float* h0  = (const float*)d_in[2];
  const float* c0  = (const float*)d_in[3];
  const float* pwr = (const float*)d_in[4];
  const float* pww = (const float*)d_in[5];
  const float* mem = (const float*)d_in[6];
  const float* Wih = (const float*)d_in[7];
  const float* Whh = (const float*)d_in[8];
  const float* bih = (const float*)d_in[9];
  const float* bhh = (const float*)d_in[10];
  const float* Wr  = (const float*)d_in[11];
  const float* br  = (const float*)d_in[12];
  const float* Ww  = (const float*)d_in[13];
  const float* bw  = (const float*)d_in[14];
  const float* fcW = (const float*)d_in[15];
  const float* fcb = (const float*)d_in[16];
  float* out = (float*)d_out;

  float* ws = (float*)d_ws;
  size_t off = 0;
  auto alloc = [&](size_t n){ float* p = ws + off; off += n; return p; };
  const size_t S = (size_t)BB*NN;
  float* GPART = alloc((size_t)4*BB*JTOT);
  float* CTRL  = alloc((size_t)BB*HH);
  float* RPART = alloc((size_t)4*BB*RSTR);
  float* COEF8 = alloc((size_t)BB*MM*8);
  float* SCAL  = alloc((size_t)4*BB*8);
  float* OUT9  = alloc(9*S);
  float* WR0   = alloc(S);
  float* WW0   = alloc(S);     // must stay adjacent to WR0
  float* WR1   = alloc(S);
  float* PART  = alloc((size_t)BB*CHUNKS*PROW);
  (void)ws_size; (void)in_sizes; (void)n_in; (void)out_size; (void)WW0;

  k_lstm_split<<<dim3(64,4), 128, 0, stream>>>(x, pr, h0, Wih, Whh, GPART);
  k_ctrl<<<(BB*HH+255)/256, 256, 0, stream>>>(GPART, bih, bhh, c0, CTRL);
  k_head_split<<<dim3(21,4), 128, 0, stream>>>(CTRL, Wr, Ww, RPART);
  k_params<<<BB, 256, 0, stream>>>(RPART, br, bw, COEF8, SCAL);
  k_passA<<<CHUNKS*BB, 256, 0, stream>>>(mem, COEF8, OUT9);
  k_addr<<<2*BB, 512, 0, stream>>>(OUT9, SCAL, pwr, pww, WR0, WR1);
  k_passF<<<CHUNKS*BB, 256, 0, stream>>>(mem, WR0, WR1, WW0, PART);
  k_tail<<<BB, 256, 0, stream>>>(PART, COEF8, fcW, fcb, out);
}